// Round 3
// baseline (54.763 us; speedup 1.0000x reference)
//
#include <hip/hip_runtime.h>

// Problem constants (fixed-shape bench)
#define BB 2
#define HH 8
#define LL 32
#define CHK 64
#define DD 64
#define MAX_REL 32
#define NN 2048            // LL*CHK
#define RPW 8              // rows per wave

typedef float f32x4 __attribute__((ext_vector_type(4)));

// Wave-autonomous: each 64-lane wave owns RPW consecutive output rows (all in
// one chunk q). No LDS, no barriers. Lane layout: part = lane&7 (8-float slice
// of D), kgrp = lane>>3. Pass p computes dot for k = p*8+kgrp; store phase
// broadcasts via __shfl with compile-time register index s[j>>1].
__global__ __launch_bounds__(256) void relpos_kernel(
    const float* __restrict__ x,      // [B,H,N,D]
    const int*   __restrict__ pos,    // [B,L,L]
    const float* __restrict__ table,  // [2*MAX_REL+1, D]
    float*       __restrict__ out)    // [B,H,N,N]
{
    const int wid  = blockIdx.x * 4 + (threadIdx.x >> 6);  // 0..4095
    const int lane = threadIdx.x & 63;
    const int part = lane & 7;
    const int kgrp = lane >> 3;

    const int row0 = wid * RPW;                 // first of 8 consecutive rows
    const int q    = (row0 >> 6) & (LL - 1);    // chunk (row-block) index
    const int b    = row0 >> 14;                // rows per b = H*N = 16384

    // Preload embedding fragments: e[p] covers k = p*8 + kgrp, d-slice part*8.
    f32x4 ea[4], eb[4];
    const int pbase = (b * LL + q) * LL;
    #pragma unroll
    for (int p = 0; p < 4; ++p) {
        int pp = pos[pbase + p * 8 + kgrp];
        pp = min(max(pp, -MAX_REL), MAX_REL) + MAX_REL;
        const float* erow = table + pp * DD + part * 8;
        ea[p] = *(const f32x4*)(erow);
        eb[p] = *(const f32x4*)(erow + 4);
    }

    const float* xbase = x + (size_t)row0 * DD + part * 8;

    // Software pipeline: prefetch row r+1's x while computing/storing row r.
    f32x4 xa = *(const f32x4*)(xbase);
    f32x4 xb = *(const f32x4*)(xbase + 4);

    for (int r = 0; r < RPW; ++r) {
        const f32x4 cxa = xa, cxb = xb;
        if (r + 1 < RPW) {
            xa = *(const f32x4*)(xbase + (r + 1) * DD);
            xb = *(const f32x4*)(xbase + (r + 1) * DD + 4);
        }

        float s[4];
        #pragma unroll
        for (int p = 0; p < 4; ++p) {
            float t = cxa.x * ea[p].x + cxa.y * ea[p].y
                    + cxa.z * ea[p].z + cxa.w * ea[p].w
                    + cxb.x * eb[p].x + cxb.y * eb[p].y
                    + cxb.z * eb[p].z + cxb.w * eb[p].w;
            t += __shfl_xor(t, 1);
            t += __shfl_xor(t, 2);
            t += __shfl_xor(t, 4);
            s[p] = t;               // full dot for k = p*8 + kgrp
        }

        // Store row: float4 column c4 = 64*j + lane needs dot kk = 4j+(lane>>4).
        // Register index kk>>3 == j>>1 (compile-time); source lane dynamic.
        float* orow = out + (size_t)(row0 + r) * NN;
        #pragma unroll
        for (int j = 0; j < 8; ++j) {
            int src = ((4 * j + (lane >> 4)) & 7) << 3;
            float v = __shfl(s[j >> 1], src);
            f32x4 v4 = {v, v, v, v};
            __builtin_nontemporal_store(v4, (f32x4*)orow + j * 64 + lane);
        }
    }
}

extern "C" void kernel_launch(void* const* d_in, const int* in_sizes, int n_in,
                              void* d_out, int out_size, void* d_ws, size_t ws_size,
                              hipStream_t stream) {
    const float* x     = (const float*)d_in[0];
    const int*   pos   = (const int*)d_in[1];
    const float* table = (const float*)d_in[2];
    float*       out   = (float*)d_out;

    // 4096 waves x 8 rows = 32768 rows; 1024 blocks (4 waves each).
    dim3 grid(BB * HH * NN / RPW / 4);
    relpos_kernel<<<grid, 256, 0, stream>>>(x, pos, table, out);
}